// Round 4
// baseline (93.446 us; speedup 1.0000x reference)
//
#include <hip/hip_runtime.h>
#include <hip/hip_bf16.h>
#include <math.h>

#define BB 8
#define NN 2048
#define IND 128
#define OUTD 64
#define NEG 0.2f

typedef __attribute__((ext_vector_type(8))) short short8;
typedef __attribute__((ext_vector_type(4))) float f32x4;

// RNE float -> bf16 (scalar, used in proj epilogue)
__device__ __forceinline__ unsigned short f2bf(float f) {
    unsigned int u = __float_as_uint(f);
    u += 0x7fffu + ((u >> 16) & 1u);
    return (unsigned short)(u >> 16);
}

// packed RNE f32x2 -> bf16x2 (v_cvt_pk_bf16_f32 on gfx950)
__device__ __forceinline__ unsigned int pk_bf16(float a, float b) {
    union { __hip_bfloat162 h; unsigned int u; } cv;
    cv.h = __float22bfloat162_rn(make_float2(a, b));
    return cv.u;
}

// ---------------------------------------------------------------------------
// Kernel 1: hp = h @ W_fc + b_fc ; s = hp@a_src ; d = hp@a_dst
// LDS-tiled fp32 GEMM: 64 rows/block, 256 threads, acc[4 rows][4 cols].
// All LDS reads are b128 (h and W as float4) so the VALU, not the LDS pipe,
// is the limiter. Also emits:
//   hpT2 : chunk-tiled bf16 [b][cj=j/8][o][j%8] for MFMA B-frags
//   s    : hp @ a_src  (fp32)
//   F,H  : exp(d_j), exp(NEG*d_j) for the factorized leaky-softmax weights
// ---------------------------------------------------------------------------
__global__ __launch_bounds__(256) void gat_proj_kernel(
    const float* __restrict__ h, const float* __restrict__ W,
    const float* __restrict__ bfc, const float* __restrict__ asrc,
    const float* __restrict__ adst,
    unsigned short* __restrict__ hpT2, float* __restrict__ s,
    float* __restrict__ F, float* __restrict__ H)
{
    __shared__ float Wl[IND * OUTD];   // 32 KB  [k][o]
    __shared__ float hl[64 * 132];     // 33.8 KB [r][k], pad 132 (16B-aligned)

    const int t  = threadIdx.x;
    const int R0 = blockIdx.x * 64;

    const float4* W4 = (const float4*)W;
    float4*       Wl4 = (float4*)Wl;
    #pragma unroll
    for (int k2 = 0; k2 < 8; ++k2) Wl4[t + k2 * 256] = W4[t + k2 * 256];

    const float4* h4 = (const float4*)(h + (size_t)R0 * IND);
    #pragma unroll
    for (int k2 = 0; k2 < 8; ++k2) {
        const int idx = t + k2 * 256;      // float4 index
        const int row = idx >> 5, c4 = idx & 31;
        *(float4*)&hl[row * 132 + c4 * 4] = h4[idx];
    }
    __syncthreads();

    const int r0 = (t >> 4) * 4;           // 4 rows per thread
    const int o0 = (t & 15) * 4;           // 4 cols per thread
    const float4 bias = *(const float4*)(bfc + o0);
    float4 a0 = bias, a1 = bias, a2 = bias, a3 = bias;

    #pragma unroll 2
    for (int kc = 0; kc < IND; kc += 4) {
        const float4 w0 = *(const float4*)&Wl[(kc + 0) * OUTD + o0];
        const float4 w1 = *(const float4*)&Wl[(kc + 1) * OUTD + o0];
        const float4 w2 = *(const float4*)&Wl[(kc + 2) * OUTD + o0];
        const float4 w3 = *(const float4*)&Wl[(kc + 3) * OUTD + o0];
        const float4 h0 = *(const float4*)&hl[(r0 + 0) * 132 + kc];
        const float4 h1 = *(const float4*)&hl[(r0 + 1) * 132 + kc];
        const float4 h2 = *(const float4*)&hl[(r0 + 2) * 132 + kc];
        const float4 h3 = *(const float4*)&hl[(r0 + 3) * 132 + kc];

        a0.x = fmaf(h0.x, w0.x, a0.x); a0.y = fmaf(h0.x, w0.y, a0.y);
        a0.z = fmaf(h0.x, w0.z, a0.z); a0.w = fmaf(h0.x, w0.w, a0.w);
        a0.x = fmaf(h0.y, w1.x, a0.x); a0.y = fmaf(h0.y, w1.y, a0.y);
        a0.z = fmaf(h0.y, w1.z, a0.z); a0.w = fmaf(h0.y, w1.w, a0.w);
        a0.x = fmaf(h0.z, w2.x, a0.x); a0.y = fmaf(h0.z, w2.y, a0.y);
        a0.z = fmaf(h0.z, w2.z, a0.z); a0.w = fmaf(h0.z, w2.w, a0.w);
        a0.x = fmaf(h0.w, w3.x, a0.x); a0.y = fmaf(h0.w, w3.y, a0.y);
        a0.z = fmaf(h0.w, w3.z, a0.z); a0.w = fmaf(h0.w, w3.w, a0.w);

        a1.x = fmaf(h1.x, w0.x, a1.x); a1.y = fmaf(h1.x, w0.y, a1.y);
        a1.z = fmaf(h1.x, w0.z, a1.z); a1.w = fmaf(h1.x, w0.w, a1.w);
        a1.x = fmaf(h1.y, w1.x, a1.x); a1.y = fmaf(h1.y, w1.y, a1.y);
        a1.z = fmaf(h1.y, w1.z, a1.z); a1.w = fmaf(h1.y, w1.w, a1.w);
        a1.x = fmaf(h1.z, w2.x, a1.x); a1.y = fmaf(h1.z, w2.y, a1.y);
        a1.z = fmaf(h1.z, w2.z, a1.z); a1.w = fmaf(h1.z, w2.w, a1.w);
        a1.x = fmaf(h1.w, w3.x, a1.x); a1.y = fmaf(h1.w, w3.y, a1.y);
        a1.z = fmaf(h1.w, w3.z, a1.z); a1.w = fmaf(h1.w, w3.w, a1.w);

        a2.x = fmaf(h2.x, w0.x, a2.x); a2.y = fmaf(h2.x, w0.y, a2.y);
        a2.z = fmaf(h2.x, w0.z, a2.z); a2.w = fmaf(h2.x, w0.w, a2.w);
        a2.x = fmaf(h2.y, w1.x, a2.x); a2.y = fmaf(h2.y, w1.y, a2.y);
        a2.z = fmaf(h2.y, w1.z, a2.z); a2.w = fmaf(h2.y, w1.w, a2.w);
        a2.x = fmaf(h2.z, w2.x, a2.x); a2.y = fmaf(h2.z, w2.y, a2.y);
        a2.z = fmaf(h2.z, w2.z, a2.z); a2.w = fmaf(h2.z, w2.w, a2.w);
        a2.x = fmaf(h2.w, w3.x, a2.x); a2.y = fmaf(h2.w, w3.y, a2.y);
        a2.z = fmaf(h2.w, w3.z, a2.z); a2.w = fmaf(h2.w, w3.w, a2.w);

        a3.x = fmaf(h3.x, w0.x, a3.x); a3.y = fmaf(h3.x, w0.y, a3.y);
        a3.z = fmaf(h3.x, w0.z, a3.z); a3.w = fmaf(h3.x, w0.w, a3.w);
        a3.x = fmaf(h3.y, w1.x, a3.x); a3.y = fmaf(h3.y, w1.y, a3.y);
        a3.z = fmaf(h3.y, w1.z, a3.z); a3.w = fmaf(h3.y, w1.w, a3.w);
        a3.x = fmaf(h3.z, w2.x, a3.x); a3.y = fmaf(h3.z, w2.y, a3.y);
        a3.z = fmaf(h3.z, w2.z, a3.z); a3.w = fmaf(h3.z, w2.w, a3.w);
        a3.x = fmaf(h3.w, w3.x, a3.x); a3.y = fmaf(h3.w, w3.y, a3.y);
        a3.z = fmaf(h3.w, w3.z, a3.z); a3.w = fmaf(h3.w, w3.w, a3.w);
    }

    // ---- write hpT2 chunk-tiled bf16: [b][cj][o][8] ----
    const int b   = R0 >> 11;
    const int jb0 = (R0 & 2047) + r0;
    const int cj  = jb0 >> 3;
    const int sub = jb0 & 7;               // 0 or 4
    unsigned short* cbase = hpT2 + (((size_t)(b * 256 + cj)) * OUTD) * 8;
    {
        ushort4 v;
        v.x = f2bf(a0.x); v.y = f2bf(a1.x); v.z = f2bf(a2.x); v.w = f2bf(a3.x);
        *(ushort4*)(cbase + (o0 + 0) * 8 + sub) = v;
        v.x = f2bf(a0.y); v.y = f2bf(a1.y); v.z = f2bf(a2.y); v.w = f2bf(a3.y);
        *(ushort4*)(cbase + (o0 + 1) * 8 + sub) = v;
        v.x = f2bf(a0.z); v.y = f2bf(a1.z); v.z = f2bf(a2.z); v.w = f2bf(a3.z);
        *(ushort4*)(cbase + (o0 + 2) * 8 + sub) = v;
        v.x = f2bf(a0.w); v.y = f2bf(a1.w); v.z = f2bf(a2.w); v.w = f2bf(a3.w);
        *(ushort4*)(cbase + (o0 + 3) * 8 + sub) = v;
    }

    // ---- s, F, H ----
    const float4 as4 = *(const float4*)(asrc + o0);
    const float4 ad4 = *(const float4*)(adst + o0);
    float vs[4], vd[4];
    vs[0] = a0.x*as4.x + a0.y*as4.y + a0.z*as4.z + a0.w*as4.w;
    vs[1] = a1.x*as4.x + a1.y*as4.y + a1.z*as4.z + a1.w*as4.w;
    vs[2] = a2.x*as4.x + a2.y*as4.y + a2.z*as4.z + a2.w*as4.w;
    vs[3] = a3.x*as4.x + a3.y*as4.y + a3.z*as4.z + a3.w*as4.w;
    vd[0] = a0.x*ad4.x + a0.y*ad4.y + a0.z*ad4.z + a0.w*ad4.w;
    vd[1] = a1.x*ad4.x + a1.y*ad4.y + a1.z*ad4.z + a1.w*ad4.w;
    vd[2] = a2.x*ad4.x + a2.y*ad4.y + a2.z*ad4.z + a2.w*ad4.w;
    vd[3] = a3.x*ad4.x + a3.y*ad4.y + a3.z*ad4.z + a3.w*ad4.w;
    #pragma unroll
    for (int msk = 1; msk <= 8; msk <<= 1) {
        #pragma unroll
        for (int r = 0; r < 4; ++r) {
            vs[r] += __shfl_xor(vs[r], msk);
            vd[r] += __shfl_xor(vd[r], msk);
        }
    }
    if ((t & 15) == 0) {
        #pragma unroll
        for (int r = 0; r < 4; ++r) {
            s[R0 + r0 + r] = vs[r];
            F[R0 + r0 + r] = __expf(vd[r]);
            H[R0 + r0 + r] = __expf(NEG * vd[r]);
        }
    }
}

// ---------------------------------------------------------------------------
// Kernel 2: softmax(leakyrelu(s_i+d_j+b)) @ hp via MFMA, k-split across 4
// waves + LDS combine. Weight factorization (exact):
//   exp(leaky(x)) = max(E_i*F_j, G_i*H_j),
//   E=exp(s_i+b), G=exp(NEG*(s_i+b)), F=exp(d_j), H=exp(NEG*d_j)
// — zero transcendentals in the j-loop. Denominator = 5th MFMA with B=ones
// (sums the bf16-rounded weights: numerator-consistent).
// ---------------------------------------------------------------------------
__global__ __launch_bounds__(256) void gat_attn_kernel(
    const unsigned short* __restrict__ hpT2, const float* __restrict__ s,
    const float* __restrict__ F, const float* __restrict__ H,
    const float* __restrict__ battn_p, float* __restrict__ out)
{
    __shared__ float accl[4][16 * 65];   // per-wave partials, row stride 65
    __shared__ float ll[4][16];          // per-wave denominator partials

    const int t    = threadIdx.x;
    const int lane = t & 63;
    const int wv   = t >> 6;
    const int tile = blockIdx.x;           // 0..1023
    const int b    = tile >> 7;            // 128 i-tiles per batch
    const int i0   = (tile & 127) * 16;
    const int m    = lane & 15;            // A-frag row within tile
    const int kc   = lane >> 4;            // k-chunk quad (0..3)

    const float battn = battn_p[0];
    const float sm = s[b * NN + i0 + m] + battn;
    const float Ei = __expf(sm);
    const float Gi = __expf(NEG * sm);
    const float* Fb = F + b * NN;
    const float* Hb = H + b * NN;
    const unsigned short* hb = hpT2 + (size_t)b * 256 * OUTD * 8;

    short8 ones;
    #pragma unroll
    for (int q = 0; q < 8; ++q) ones[q] = (short)0x3F80;  // bf16 1.0

    f32x4 acc0 = {0.f, 0.f, 0.f, 0.f};
    f32x4 acc1 = {0.f, 0.f, 0.f, 0.f};
    f32x4 acc2 = {0.f, 0.f, 0.f, 0.f};
    f32x4 acc3 = {0.f, 0.f, 0.f, 0.f};
    f32x4 accl4 = {0.f, 0.f, 0.f, 0.f};

    const int jbase = wv * (NN / 4);       // this wave's 512-wide j range

    #pragma unroll 2
    for (int it = 0; it < NN / 4 / 32; ++it) {
        const int j0 = jbase + it * 32;
        // --- A-frag: w[i0+m][j0+kc*8 .. +7] = max(Ei*F, Gi*H) ---
        const float4 Fa = *(const float4*)(Fb + j0 + kc * 8);
        const float4 Fc = *(const float4*)(Fb + j0 + kc * 8 + 4);
        const float4 Ha = *(const float4*)(Hb + j0 + kc * 8);
        const float4 Hc = *(const float4*)(Hb + j0 + kc * 8 + 4);
        float wf[8];
        wf[0] = fmaxf(Ei * Fa.x, Gi * Ha.x);
        wf[1] = fmaxf(Ei * Fa.y, Gi * Ha.y);
        wf[2] = fmaxf(Ei * Fa.z, Gi * Ha.z);
        wf[3] = fmaxf(Ei * Fa.w, Gi * Ha.w);
        wf[4] = fmaxf(Ei * Fc.x, Gi * Hc.x);
        wf[5] = fmaxf(Ei * Fc.y, Gi * Hc.y);
        wf[6] = fmaxf(Ei * Fc.z, Gi * Hc.z);
        wf[7] = fmaxf(Ei * Fc.w, Gi * Hc.w);

        union { short8 s8; unsigned int u[4]; } af;
        af.u[0] = pk_bf16(wf[0], wf[1]);
        af.u[1] = pk_bf16(wf[2], wf[3]);
        af.u[2] = pk_bf16(wf[4], wf[5]);
        af.u[3] = pk_bf16(wf[6], wf[7]);

        // --- B-frags: hp[j0+kc*8 .. +7][ot*16+m], coalesced 16B/lane ---
        const size_t cb = ((size_t)((j0 >> 3) + kc)) * OUTD * 8;
        const short8 bf0 = *(const short8*)(hb + cb + (0 * 16 + m) * 8);
        const short8 bf1 = *(const short8*)(hb + cb + (1 * 16 + m) * 8);
        const short8 bf2 = *(const short8*)(hb + cb + (2 * 16 + m) * 8);
        const short8 bf3 = *(const short8*)(hb + cb + (3 * 16 + m) * 8);

        acc0 = __builtin_amdgcn_mfma_f32_16x16x32_bf16(af.s8, bf0, acc0, 0, 0, 0);
        acc1 = __builtin_amdgcn_mfma_f32_16x16x32_bf16(af.s8, bf1, acc1, 0, 0, 0);
        acc2 = __builtin_amdgcn_mfma_f32_16x16x32_bf16(af.s8, bf2, acc2, 0, 0, 0);
        acc3 = __builtin_amdgcn_mfma_f32_16x16x32_bf16(af.s8, bf3, acc3, 0, 0, 0);
        accl4 = __builtin_amdgcn_mfma_f32_16x16x32_bf16(af.s8, ones, accl4, 0, 0, 0);
    }

    // denominator partials: D[row][0] lives in lanes with m==0,
    // row = kc*4 + reg  (C layout: col=lane&15, row=(lane>>4)*4+reg)
    if (m == 0) {
        #pragma unroll
        for (int r = 0; r < 4; ++r) ll[wv][kc * 4 + r] = accl4[r];
    }

    #pragma unroll
    for (int r = 0; r < 4; ++r) {
        const int row = kc * 4 + r;
        accl[wv][row * 65 + 0 * 16 + m] = acc0[r];
        accl[wv][row * 65 + 1 * 16 + m] = acc1[r];
        accl[wv][row * 65 + 2 * 16 + m] = acc2[r];
        accl[wv][row * 65 + 3 * 16 + m] = acc3[r];
    }
    __syncthreads();

    // epilogue: combine 4 wave partials, divide, ELU, store
    const int col = t & 63;
    const int r0e = (t >> 6) * 4;
    float* ob = out + (((size_t)b * NN + i0) * OUTD);
    #pragma unroll
    for (int r = 0; r < 4; ++r) {
        const int row = r0e + r;
        const float lsum = (ll[0][row] + ll[1][row]) + (ll[2][row] + ll[3][row]);
        float v = (accl[0][row * 65 + col] + accl[1][row * 65 + col]) +
                  (accl[2][row * 65 + col] + accl[3][row * 65 + col]);
        v /= lsum;
        v = (v > 0.f) ? v : expm1f(v);
        ob[(size_t)row * OUTD + col] = v;
    }
}

// ---------------------------------------------------------------------------
extern "C" void kernel_launch(void* const* d_in, const int* in_sizes, int n_in,
                              void* d_out, int out_size, void* d_ws, size_t ws_size,
                              hipStream_t stream)
{
    const float* h     = (const float*)d_in[0];
    const float* W     = (const float*)d_in[1];
    const float* bfc   = (const float*)d_in[2];
    const float* asrc  = (const float*)d_in[3];
    const float* adst  = (const float*)d_in[4];
    const float* battn = (const float*)d_in[5];
    float* out = (float*)d_out;

    unsigned short* hpT2 = (unsigned short*)d_ws;            // 2 MB bf16 tiled
    float* s = (float*)((char*)d_ws + (size_t)BB * NN * OUTD * 2);
    float* F = s + (size_t)BB * NN;
    float* H = F + (size_t)BB * NN;

    gat_proj_kernel<<<(BB * NN) / 64, 256, 0, stream>>>(h, W, bfc, asrc, adst,
                                                        hpT2, s, F, H);
    gat_attn_kernel<<<BB * NN / 16, 256, 0, stream>>>(hpT2, s, F, H, battn, out);
}

// Round 5
// 91.555 us; speedup vs baseline: 1.0206x; 1.0206x over previous
//
#include <hip/hip_runtime.h>
#include <hip/hip_bf16.h>
#include <math.h>

#define BB 8
#define NN 2048
#define IND 128
#define OUTD 64
#define NEG 0.2f

typedef __attribute__((ext_vector_type(8))) short short8;
typedef __attribute__((ext_vector_type(4))) float f32x4;

// RNE float -> bf16 (scalar, used in proj epilogue)
__device__ __forceinline__ unsigned short f2bf(float f) {
    unsigned int u = __float_as_uint(f);
    u += 0x7fffu + ((u >> 16) & 1u);
    return (unsigned short)(u >> 16);
}

// packed RNE f32x2 -> bf16x2 (v_cvt_pk_bf16_f32 on gfx950)
__device__ __forceinline__ unsigned int pk_bf16(float a, float b) {
    union { __hip_bfloat162 h; unsigned int u; } cv;
    cv.h = __float22bfloat162_rn(make_float2(a, b));
    return cv.u;
}

// ---------------------------------------------------------------------------
// Kernel 1: hp = h @ W_fc + b_fc ; s = hp@a_src ; d -> F=exp(d), H=exp(NEG*d)
// 32 rows/block (256 blocks: full GPU, was 128 = half idle). 2 rows x 4 cols
// per thread; all LDS reads b128: 6 b128 : 32 FMA per k-step.
// Emits hpT2 chunk-tiled bf16 [b][cj=j/8][o][j%8] for MFMA B-frags.
// ---------------------------------------------------------------------------
__global__ __launch_bounds__(256) void gat_proj_kernel(
    const float* __restrict__ h, const float* __restrict__ W,
    const float* __restrict__ bfc, const float* __restrict__ asrc,
    const float* __restrict__ adst,
    unsigned short* __restrict__ hpT2, float* __restrict__ s,
    float* __restrict__ F, float* __restrict__ H)
{
    __shared__ float Wl[IND * OUTD];   // 32 KB  [k][o]
    __shared__ float hl[32 * 132];     // 16.9 KB [r][k], pad 132 (16B-aligned)

    const int t  = threadIdx.x;
    const int R0 = blockIdx.x * 32;

    const float4* W4 = (const float4*)W;
    float4*       Wl4 = (float4*)Wl;
    #pragma unroll
    for (int k2 = 0; k2 < 8; ++k2) Wl4[t + k2 * 256] = W4[t + k2 * 256];

    const float4* h4 = (const float4*)(h + (size_t)R0 * IND);
    #pragma unroll
    for (int k2 = 0; k2 < 4; ++k2) {
        const int idx = t + k2 * 256;      // float4 index
        const int row = idx >> 5, c4 = idx & 31;
        *(float4*)&hl[row * 132 + c4 * 4] = h4[idx];
    }
    __syncthreads();

    const int r0 = (t >> 4) * 2;           // 2 rows per thread
    const int o0 = (t & 15) * 4;           // 4 cols per thread
    const float4 bias = *(const float4*)(bfc + o0);
    float4 a0 = bias, a1 = bias;

    #pragma unroll 2
    for (int kc = 0; kc < IND; kc += 4) {
        const float4 w0 = *(const float4*)&Wl[(kc + 0) * OUTD + o0];
        const float4 w1 = *(const float4*)&Wl[(kc + 1) * OUTD + o0];
        const float4 w2 = *(const float4*)&Wl[(kc + 2) * OUTD + o0];
        const float4 w3 = *(const float4*)&Wl[(kc + 3) * OUTD + o0];
        const float4 h0 = *(const float4*)&hl[(r0 + 0) * 132 + kc];
        const float4 h1 = *(const float4*)&hl[(r0 + 1) * 132 + kc];

        a0.x = fmaf(h0.x, w0.x, a0.x); a0.y = fmaf(h0.x, w0.y, a0.y);
        a0.z = fmaf(h0.x, w0.z, a0.z); a0.w = fmaf(h0.x, w0.w, a0.w);
        a0.x = fmaf(h0.y, w1.x, a0.x); a0.y = fmaf(h0.y, w1.y, a0.y);
        a0.z = fmaf(h0.y, w1.z, a0.z); a0.w = fmaf(h0.y, w1.w, a0.w);
        a0.x = fmaf(h0.z, w2.x, a0.x); a0.y = fmaf(h0.z, w2.y, a0.y);
        a0.z = fmaf(h0.z, w2.z, a0.z); a0.w = fmaf(h0.z, w2.w, a0.w);
        a0.x = fmaf(h0.w, w3.x, a0.x); a0.y = fmaf(h0.w, w3.y, a0.y);
        a0.z = fmaf(h0.w, w3.z, a0.z); a0.w = fmaf(h0.w, w3.w, a0.w);

        a1.x = fmaf(h1.x, w0.x, a1.x); a1.y = fmaf(h1.x, w0.y, a1.y);
        a1.z = fmaf(h1.x, w0.z, a1.z); a1.w = fmaf(h1.x, w0.w, a1.w);
        a1.x = fmaf(h1.y, w1.x, a1.x); a1.y = fmaf(h1.y, w1.y, a1.y);
        a1.z = fmaf(h1.y, w1.z, a1.z); a1.w = fmaf(h1.y, w1.w, a1.w);
        a1.x = fmaf(h1.z, w2.x, a1.x); a1.y = fmaf(h1.z, w2.y, a1.y);
        a1.z = fmaf(h1.z, w2.z, a1.z); a1.w = fmaf(h1.z, w2.w, a1.w);
        a1.x = fmaf(h1.w, w3.x, a1.x); a1.y = fmaf(h1.w, w3.y, a1.y);
        a1.z = fmaf(h1.w, w3.z, a1.z); a1.w = fmaf(h1.w, w3.w, a1.w);
    }

    // ---- write hpT2 chunk-tiled bf16: [b][cj][o][8], 2 rows -> ushort2 ----
    const int b   = R0 >> 11;
    const int jb0 = (R0 & 2047) + r0;
    const int cj  = jb0 >> 3;
    const int sub = jb0 & 7;               // even
    unsigned short* cbase = hpT2 + (((size_t)(b * 256 + cj)) * OUTD) * 8;
    {
        ushort2 v;
        v.x = f2bf(a0.x); v.y = f2bf(a1.x);
        *(ushort2*)(cbase + (o0 + 0) * 8 + sub) = v;
        v.x = f2bf(a0.y); v.y = f2bf(a1.y);
        *(ushort2*)(cbase + (o0 + 1) * 8 + sub) = v;
        v.x = f2bf(a0.z); v.y = f2bf(a1.z);
        *(ushort2*)(cbase + (o0 + 2) * 8 + sub) = v;
        v.x = f2bf(a0.w); v.y = f2bf(a1.w);
        *(ushort2*)(cbase + (o0 + 3) * 8 + sub) = v;
    }

    // ---- s, F, H ----
    const float4 as4 = *(const float4*)(asrc + o0);
    const float4 ad4 = *(const float4*)(adst + o0);
    float vs[2], vd[2];
    vs[0] = a0.x*as4.x + a0.y*as4.y + a0.z*as4.z + a0.w*as4.w;
    vs[1] = a1.x*as4.x + a1.y*as4.y + a1.z*as4.z + a1.w*as4.w;
    vd[0] = a0.x*ad4.x + a0.y*ad4.y + a0.z*ad4.z + a0.w*ad4.w;
    vd[1] = a1.x*ad4.x + a1.y*ad4.y + a1.z*ad4.z + a1.w*ad4.w;
    #pragma unroll
    for (int msk = 1; msk <= 8; msk <<= 1) {
        vs[0] += __shfl_xor(vs[0], msk);
        vs[1] += __shfl_xor(vs[1], msk);
        vd[0] += __shfl_xor(vd[0], msk);
        vd[1] += __shfl_xor(vd[1], msk);
    }
    if ((t & 15) == 0) {
        #pragma unroll
        for (int r = 0; r < 2; ++r) {
            s[R0 + r0 + r] = vs[r];
            F[R0 + r0 + r] = __expf(vd[r]);
            H[R0 + r0 + r] = __expf(NEG * vd[r]);
        }
    }
}

// ---------------------------------------------------------------------------
// Kernel 2: softmax(leakyrelu(s_i+d_j+b)) @ hp via MFMA.
// Each wave: 64 rows (4 A-tiles) x 512-j range -> each B-frag load feeds 4
// A-tiles (L2 traffic /4 vs 1-tile). j-split x4 across waves, LDS combine.
// Weights factorized exactly: exp(leaky(x)) = max(E_i*F_j, G_i*H_j).
// Denominator via ones-B MFMA (numerator-consistent bf16 row sums).
// ---------------------------------------------------------------------------
__global__ __launch_bounds__(256) void gat_attn_kernel(
    const unsigned short* __restrict__ hpT2, const float* __restrict__ s,
    const float* __restrict__ F, const float* __restrict__ H,
    const float* __restrict__ battn_p, float* __restrict__ out)
{
    __shared__ float accl[4][64 * 66];   // 67.6 KB: per-wave partials
    __shared__ float ll[4][64];          // per-wave denominator partials

    const int t    = threadIdx.x;
    const int lane = t & 63;
    const int wv   = t >> 6;
    const int blk  = blockIdx.x;           // 0..255
    const int b    = blk >> 5;             // 32 row-groups per batch
    const int i0   = (blk & 31) * 64;
    const int m    = lane & 15;
    const int kc   = lane >> 4;            // k-chunk quad (0..3)

    const float battn = battn_p[0];
    float E[4], G[4];
    #pragma unroll
    for (int T = 0; T < 4; ++T) {
        const float smv = s[b * NN + i0 + T * 16 + m] + battn;
        E[T] = __expf(smv);
        G[T] = __expf(NEG * smv);
    }
    const float* Fb = F + b * NN;
    const float* Hb = H + b * NN;
    const unsigned short* hb = hpT2 + (size_t)b * 256 * OUTD * 8;

    short8 ones;
    #pragma unroll
    for (int q = 0; q < 8; ++q) ones[q] = (short)0x3F80;  // bf16 1.0

    f32x4 acc[4][4];                       // [tile][ot]
    f32x4 dacc[4];                         // [tile] denominator
    #pragma unroll
    for (int T = 0; T < 4; ++T) {
        dacc[T] = (f32x4){0.f, 0.f, 0.f, 0.f};
        #pragma unroll
        for (int ot = 0; ot < 4; ++ot) acc[T][ot] = (f32x4){0.f, 0.f, 0.f, 0.f};
    }

    const int jbase = wv * (NN / 4);       // this wave's 512-wide j range

    #pragma unroll 2
    for (int it = 0; it < NN / 4 / 32; ++it) {
        const int j0 = jbase + it * 32;
        // --- B-frags first (longest latency): hp[j0+kc*8..+7][ot*16+m] ---
        const size_t cb = ((size_t)((j0 >> 3) + kc)) * OUTD * 8;
        const short8 bf0 = *(const short8*)(hb + cb + (0 * 16 + m) * 8);
        const short8 bf1 = *(const short8*)(hb + cb + (1 * 16 + m) * 8);
        const short8 bf2 = *(const short8*)(hb + cb + (2 * 16 + m) * 8);
        const short8 bf3 = *(const short8*)(hb + cb + (3 * 16 + m) * 8);

        const float4 Fa = *(const float4*)(Fb + j0 + kc * 8);
        const float4 Fc = *(const float4*)(Fb + j0 + kc * 8 + 4);
        const float4 Ha = *(const float4*)(Hb + j0 + kc * 8);
        const float4 Hc = *(const float4*)(Hb + j0 + kc * 8 + 4);

        #pragma unroll
        for (int T = 0; T < 4; ++T) {
            const float Ei = E[T], Gi = G[T];
            float wf[8];
            wf[0] = fmaxf(Ei * Fa.x, Gi * Ha.x);
            wf[1] = fmaxf(Ei * Fa.y, Gi * Ha.y);
            wf[2] = fmaxf(Ei * Fa.z, Gi * Ha.z);
            wf[3] = fmaxf(Ei * Fa.w, Gi * Ha.w);
            wf[4] = fmaxf(Ei * Fc.x, Gi * Hc.x);
            wf[5] = fmaxf(Ei * Fc.y, Gi * Hc.y);
            wf[6] = fmaxf(Ei * Fc.z, Gi * Hc.z);
            wf[7] = fmaxf(Ei * Fc.w, Gi * Hc.w);

            union { short8 s8; unsigned int u[4]; } af;
            af.u[0] = pk_bf16(wf[0], wf[1]);
            af.u[1] = pk_bf16(wf[2], wf[3]);
            af.u[2] = pk_bf16(wf[4], wf[5]);
            af.u[3] = pk_bf16(wf[6], wf[7]);

            acc[T][0] = __builtin_amdgcn_mfma_f32_16x16x32_bf16(af.s8, bf0, acc[T][0], 0, 0, 0);
            acc[T][1] = __builtin_amdgcn_mfma_f32_16x16x32_bf16(af.s8, bf1, acc[T][1], 0, 0, 0);
            acc[T][2] = __builtin_amdgcn_mfma_f32_16x16x32_bf16(af.s8, bf2, acc[T][2], 0, 0, 0);
            acc[T][3] = __builtin_amdgcn_mfma_f32_16x16x32_bf16(af.s8, bf3, acc[T][3], 0, 0, 0);
            dacc[T]   = __builtin_amdgcn_mfma_f32_16x16x32_bf16(af.s8, ones, dacc[T], 0, 0, 0);
        }
    }

    // denominator partials: D column 0 lives in m==0 lanes; row = kc*4 + reg
    if (m == 0) {
        #pragma unroll
        for (int T = 0; T < 4; ++T)
            #pragma unroll
            for (int r = 0; r < 4; ++r) ll[wv][T * 16 + kc * 4 + r] = dacc[T][r];
    }

    // stride-66 pad: kc row-offset -> +8 banks, 2-way max (free)
    #pragma unroll
    for (int T = 0; T < 4; ++T) {
        #pragma unroll
        for (int r = 0; r < 4; ++r) {
            const int row = T * 16 + kc * 4 + r;
            accl[wv][row * 66 + 0 * 16 + m] = acc[T][0][r];
            accl[wv][row * 66 + 1 * 16 + m] = acc[T][1][r];
            accl[wv][row * 66 + 2 * 16 + m] = acc[T][2][r];
            accl[wv][row * 66 + 3 * 16 + m] = acc[T][3][r];
        }
    }
    __syncthreads();

    // epilogue: combine 4 wave partials, divide, ELU, store
    const int col = t & 63;
    const int r0e = (t >> 6) * 16;
    float* ob = out + (((size_t)b * NN + i0) * OUTD);
    #pragma unroll 4
    for (int r = 0; r < 16; ++r) {
        const int row = r0e + r;
        const float lsum = (ll[0][row] + ll[1][row]) + (ll[2][row] + ll[3][row]);
        float v = (accl[0][row * 66 + col] + accl[1][row * 66 + col]) +
                  (accl[2][row * 66 + col] + accl[3][row * 66 + col]);
        v /= lsum;
        v = (v > 0.f) ? v : expm1f(v);
        ob[(size_t)row * OUTD + col] = v;
    }
}

// ---------------------------------------------------------------------------
extern "C" void kernel_launch(void* const* d_in, const int* in_sizes, int n_in,
                              void* d_out, int out_size, void* d_ws, size_t ws_size,
                              hipStream_t stream)
{
    const float* h     = (const float*)d_in[0];
    const float* W     = (const float*)d_in[1];
    const float* bfc   = (const float*)d_in[2];
    const float* asrc  = (const float*)d_in[3];
    const float* adst  = (const float*)d_in[4];
    const float* battn = (const float*)d_in[5];
    float* out = (float*)d_out;

    unsigned short* hpT2 = (unsigned short*)d_ws;            // 2 MB bf16 tiled
    float* s = (float*)((char*)d_ws + (size_t)BB * NN * OUTD * 2);
    float* F = s + (size_t)BB * NN;
    float* H = F + (size_t)BB * NN;

    gat_proj_kernel<<<(BB * NN) / 32, 256, 0, stream>>>(h, W, bfc, asrc, adst,
                                                        hpT2, s, F, H);
    gat_attn_kernel<<<BB * (NN / 64), 256, 0, stream>>>(hpT2, s, F, H, battn, out);
}